// Round 7
// baseline (350.632 us; speedup 1.0000x reference)
//
#include <hip/hip_runtime.h>

// 3x3 valid conv (NCHW/OIHW) + bias + relu(y)*min(y+3,6)/6, fp32.
// x: (N=4096, C=3, 32, 32), w: (16, 3, 3, 3), out: (N, 16, 30, 30).
//
// Round 11 = Round 9 + ONE variable: nontemporal output stores.
//  - Series-wide evidence: conv_inferred tracks the 944MB fill's time
//    (ratio 0.92-1.01 across +-17% machine swings) => conv moves ~900MB,
//    not the ideal 286MB. Only conv counter capture ever (R5): FETCH 127MB
//    + WRITE 564MB = 708MB = 3x ideal. Theory: output lines are L2-cold
//    (just re-poisoned + streamed out by the fill) -> every store misses ->
//    write-allocate RFO fetch (+236MB) + writeback + partial-line
//    re-evictions. No structural change (R4-R10) touched this; hence the
//    invariant ~140us.
//  - Fix under test: __builtin_nontemporal_store (nt bit) on all output
//    stores -> no-allocate streaming writes, no RFO of poisoned lines.
//  - Everything else identical to R9: thread = horizontal 4-px group,
//    18 LDS reads/img (b128+b64 per (ic,kh)), SGPR weight window,
//    double-buffered sx, prefetch issued after the barrier, 1 barrier/img,
//    direct reg->global float2 stores, __launch_bounds__(256,4).

#define IMGS 4

typedef float v2f __attribute__((ext_vector_type(2)));

__global__ __launch_bounds__(256, 4) void conv3x3_hswish(
    const float* __restrict__ x,
    const float* __restrict__ w,
    const float* __restrict__ bias,
    float* __restrict__ out)
{
    const int tid  = threadIdx.x;
    const int img0 = blockIdx.x * IMGS;

    // Double-buffered image; +8 pad covers the tail group's b64 overread.
    __shared__ __align__(16) float sx[2][3080];

    // Slot: g = oh*8 + ow/4; threads 240..255 shadow slot 239, no store.
    const int g  = tid < 240 ? tid : 239;
    const int oh = g >> 3;
    const int ow = (g & 7) << 2;            // 0,4,...,28
    const int xrow0 = oh * 32 + ow;
    const bool active = tid < 240;
    const bool full   = ow < 28;            // ow=28 group: only px 0,1 valid

    // Bias via scalar path (uniform -> SGPR).
    float bb[16];
    #pragma unroll
    for (int oc = 0; oc < 16; ++oc) bb[oc] = bias[oc];

    // Prefetch image 0.
    float4 px0, px1, px2;
    {
        const float4* xg = (const float4*)(x + (size_t)img0 * 3072);
        px0 = xg[tid]; px1 = xg[tid + 256]; px2 = xg[tid + 512];
    }

    #pragma unroll 1
    for (int im = 0; im < IMGS; ++im) {
        float* buf = sx[im & 1];
        {   // Commit staged image (compiler inserts the vmcnt wait on px use).
            float4* s4 = (float4*)buf;
            s4[tid] = px0; s4[tid + 256] = px1; s4[tid + 512] = px2;
        }
        __syncthreads();

        // Issue next image's loads AFTER the barrier: they fly under the
        // whole compute phase, consumed at the next commit.
        if (im + 1 < IMGS) {
            const float4* xg =
                (const float4*)(x + (size_t)(img0 + im + 1) * 3072);
            px0 = xg[tid]; px1 = xg[tid + 256]; px2 = xg[tid + 512];
        }
        __builtin_amdgcn_sched_barrier(0);   // pin prefetch issue here

        float acc[4][16];
        #pragma unroll
        for (int k = 0; k < 4; ++k)
            #pragma unroll
            for (int oc = 0; oc < 16; ++oc) acc[k][oc] = 0.f;

        // Hot loop: dynamic ic, static (kh,kw); weights via s_load/SGPR.
        #pragma unroll 1
        for (int ic = 0; ic < 3; ++ic) {
            const float* __restrict__ wq = w + ic * 9;
            const float* xr = buf + (ic << 10) + xrow0;
            #pragma unroll
            for (int kh = 0; kh < 3; ++kh) {
                // 6 columns feed 3 kw x 4 px: one b128 + one b64.
                const float4 v4 = *(const float4*)(xr + kh * 32);
                const float2 v2 = *(const float2*)(xr + kh * 32 + 4);
                const float xv[6] = {v4.x, v4.y, v4.z, v4.w, v2.x, v2.y};
                #pragma unroll
                for (int kw = 0; kw < 3; ++kw) {
                    float ws[16];
                    #pragma unroll
                    for (int oc = 0; oc < 16; ++oc)
                        ws[oc] = wq[oc * 27 + kh * 3 + kw];   // uniform->SGPR
                    #pragma unroll
                    for (int k = 0; k < 4; ++k) {
                        const float xx = xv[k + kw];          // static index
                        #pragma unroll
                        for (int oc = 0; oc < 16; ++oc)
                            acc[k][oc] = fmaf(xx, ws[oc], acc[k][oc]);
                    }
                }
            }
        }

        // Epilogue: bias + hardswish*relu; NONTEMPORAL float2 stores from
        // regs (nt = no-allocate: don't RFO the poisoned, L2-cold lines).
        float* outb = out + (size_t)(img0 + im) * 14400 + oh * 30 + ow;
        if (active) {
            #pragma unroll
            for (int oc = 0; oc < 16; ++oc) {
                const float y0 = acc[0][oc] + bb[oc];
                const float y1 = acc[1][oc] + bb[oc];
                v2f r01;
                r01.x = fmaxf(y0, 0.f) * fminf(fmaf(y0, 1.f / 6.f, 0.5f), 1.f);
                r01.y = fmaxf(y1, 0.f) * fminf(fmaf(y1, 1.f / 6.f, 0.5f), 1.f);
                __builtin_nontemporal_store(r01, (v2f*)(outb + oc * 900));
                if (full) {
                    const float y2 = acc[2][oc] + bb[oc];
                    const float y3 = acc[3][oc] + bb[oc];
                    v2f r23;
                    r23.x = fmaxf(y2, 0.f) * fminf(fmaf(y2, 1.f / 6.f, 0.5f), 1.f);
                    r23.y = fmaxf(y3, 0.f) * fminf(fmaf(y3, 1.f / 6.f, 0.5f), 1.f);
                    __builtin_nontemporal_store(r23, (v2f*)(outb + oc * 900 + 2));
                }
            }
        }
        // No trailing barrier: next iteration writes the OTHER sx buffer.
    }
}

extern "C" void kernel_launch(void* const* d_in, const int* in_sizes, int n_in,
                              void* d_out, int out_size, void* d_ws, size_t ws_size,
                              hipStream_t stream) {
    const float* x    = (const float*)d_in[0];
    const float* w    = (const float*)d_in[1];
    const float* bias = (const float*)d_in[2];
    float* out        = (float*)d_out;

    const int N = in_sizes[0] / (3 * 32 * 32);  // 4096
    conv3x3_hswish<<<N / IMGS, 256, 0, stream>>>(x, w, bias, out);
}

// Round 8
// 297.494 us; speedup vs baseline: 1.1786x; 1.1786x over previous
//
#include <hip/hip_runtime.h>

// 3x3 valid conv (NCHW/OIHW) + bias + relu(y)*min(y+3,6)/6, fp32.
// x: (N=4096, C=3, 32, 32), w: (16, 3, 3, 3), out: (N, 16, 30, 30).
//
// Round 12 = Round 11 hot loop + full-line nontemporal stores.
//  - R11 counters (first clean conv capture): FETCH 24.6MB (input is
//    L3-resident, free), WRITE 404MB = 1.71x ideal, VALUBusy 22%, BW 2.8TB/s.
//    The write path IS the kernel. nt-float2 stores left 8B holes per lane
//    -> partial-sector DRAM writes, no combining. Through-L2 (R6/R9) instead
//    RFO'd the poisoned L2-cold lines -> same ~140us, the series invariant.
//  - Fix: wave-private LDS transpose (R8-proven, ZERO barriers: wave w owns
//    8 complete output rows = contiguous 960B per oc), then nt float4
//    stores: 64 lanes x 16B = 1KB of COMPLETE 64B lines per instruction.
//    Only the 16 oc-boundary lines/img (3600B % 64 != 0) stay partial (~2%).
//  - sy[wave][4 oc][240] = 15.4KB, 4 oc-chunks reuse it (in-wave ordering,
//    no barriers). LDS total 40.0KB -> still 4 blocks/CU (160KB).
//  - Everything else identical to R11/R9: 4-px groups, b128+b64 x-reads,
//    SGPR weight window, double-buffered sx, prefetch after barrier,
//    1 barrier/img, __launch_bounds__(256,4).

#define IMGS 4

typedef float v4f __attribute__((ext_vector_type(4)));

__global__ __launch_bounds__(256, 4) void conv3x3_hswish(
    const float* __restrict__ x,
    const float* __restrict__ w,
    const float* __restrict__ bias,
    float* __restrict__ out)
{
    const int tid  = threadIdx.x;
    const int lane = tid & 63;
    const int wv   = tid >> 6;              // wave 0..3
    const int img0 = blockIdx.x * IMGS;

    // Double-buffered image; +8 pad covers the tail group's b64 overread.
    __shared__ __align__(16) float sx[2][3080];
    // Wave-private epilogue staging: [wave][4 oc][240 px].
    __shared__ __align__(16) float sy[4][960];

    // Slot: g = oh*8 + ow/4; threads 240..255 shadow slot 239, no stores.
    const int g  = tid < 240 ? tid : 239;
    const int oh = g >> 3;
    const int ow = (g & 7) << 2;            // 0,4,...,28
    const int xrow0 = oh * 32 + ow;
    const bool active = tid < 240;
    const bool full   = ow < 28;            // ow=28 group: only px 0,1 valid
    const int sybase = (oh & 7) * 30 + ow;  // row within wave's 8-row slab

    // Bias via scalar path (uniform -> SGPR).
    float bb[16];
    #pragma unroll
    for (int oc = 0; oc < 16; ++oc) bb[oc] = bias[oc];

    // Prefetch image 0.
    float4 px0, px1, px2;
    {
        const float4* xg = (const float4*)(x + (size_t)img0 * 3072);
        px0 = xg[tid]; px1 = xg[tid + 256]; px2 = xg[tid + 512];
    }

    #pragma unroll 1
    for (int im = 0; im < IMGS; ++im) {
        float* buf = sx[im & 1];
        {   // Commit staged image.
            float4* s4 = (float4*)buf;
            s4[tid] = px0; s4[tid + 256] = px1; s4[tid + 512] = px2;
        }
        __syncthreads();

        // Next image's loads fly under the whole compute phase.
        if (im + 1 < IMGS) {
            const float4* xg =
                (const float4*)(x + (size_t)(img0 + im + 1) * 3072);
            px0 = xg[tid]; px1 = xg[tid + 256]; px2 = xg[tid + 512];
        }
        __builtin_amdgcn_sched_barrier(0);   // pin prefetch issue here

        float acc[4][16];
        #pragma unroll
        for (int k = 0; k < 4; ++k)
            #pragma unroll
            for (int oc = 0; oc < 16; ++oc) acc[k][oc] = 0.f;

        // Hot loop: dynamic ic, static (kh,kw); weights via s_load/SGPR.
        #pragma unroll 1
        for (int ic = 0; ic < 3; ++ic) {
            const float* __restrict__ wq = w + ic * 9;
            const float* xr = buf + (ic << 10) + xrow0;
            #pragma unroll
            for (int kh = 0; kh < 3; ++kh) {
                const float4 v4 = *(const float4*)(xr + kh * 32);
                const float2 v2 = *(const float2*)(xr + kh * 32 + 4);
                const float xv[6] = {v4.x, v4.y, v4.z, v4.w, v2.x, v2.y};
                #pragma unroll
                for (int kw = 0; kw < 3; ++kw) {
                    float ws[16];
                    #pragma unroll
                    for (int oc = 0; oc < 16; ++oc)
                        ws[oc] = wq[oc * 27 + kh * 3 + kw];   // uniform->SGPR
                    #pragma unroll
                    for (int k = 0; k < 4; ++k) {
                        const float xx = xv[k + kw];          // static index
                        #pragma unroll
                        for (int oc = 0; oc < 16; ++oc)
                            acc[k][oc] = fmaf(xx, ws[oc], acc[k][oc]);
                    }
                }
            }
        }

        // Epilogue: 4 oc-chunks. Per chunk: wave-private LDS transpose
        // (no barriers, in-wave ds ordering), then nt float4 stores of
        // contiguous full 64B lines (wave = 960B span per oc).
        float* syw  = sy[wv];
        float* outn = out + (size_t)(img0 + im) * 14400 + wv * 240;
        const int lim = (wv < 3) ? 60 : 45;  // wave 3 spans 6 rows = 180 fl
        #pragma unroll
        for (int ch = 0; ch < 4; ++ch) {
            if (active) {
                #pragma unroll
                for (int i = 0; i < 4; ++i) {
                    const int oc = ch * 4 + i;
                    const float y0 = acc[0][oc] + bb[oc];
                    const float y1 = acc[1][oc] + bb[oc];
                    float2 r01;
                    r01.x = fmaxf(y0, 0.f) * fminf(fmaf(y0, 1.f/6.f, 0.5f), 1.f);
                    r01.y = fmaxf(y1, 0.f) * fminf(fmaf(y1, 1.f/6.f, 0.5f), 1.f);
                    *(float2*)(syw + i * 240 + sybase) = r01;
                    if (full) {
                        const float y2 = acc[2][oc] + bb[oc];
                        const float y3 = acc[3][oc] + bb[oc];
                        float2 r23;
                        r23.x = fmaxf(y2, 0.f) * fminf(fmaf(y2, 1.f/6.f, 0.5f), 1.f);
                        r23.y = fmaxf(y3, 0.f) * fminf(fmaf(y3, 1.f/6.f, 0.5f), 1.f);
                        *(float2*)(syw + i * 240 + sybase + 2) = r23;
                    }
                }
            }
            if (lane < lim) {
                #pragma unroll
                for (int i = 0; i < 4; ++i) {
                    const int oc = ch * 4 + i;
                    const v4f v = *(const v4f*)(syw + i * 240 + lane * 4);
                    __builtin_nontemporal_store(
                        v, (v4f*)(outn + oc * 900 + lane * 4));
                }
            }
        }
        // No trailing barrier: next iteration writes the OTHER sx buffer,
        // and sy is wave-private.
    }
}

extern "C" void kernel_launch(void* const* d_in, const int* in_sizes, int n_in,
                              void* d_out, int out_size, void* d_ws, size_t ws_size,
                              hipStream_t stream) {
    const float* x    = (const float*)d_in[0];
    const float* w    = (const float*)d_in[1];
    const float* bias = (const float*)d_in[2];
    float* out        = (float*)d_out;

    const int N = in_sizes[0] / (3 * 32 * 32);  // 4096
    conv3x3_hswish<<<N / IMGS, 256, 0, stream>>>(x, w, bias, out);
}